// Round 1
// 245.829 us; speedup vs baseline: 1.0667x; 1.0667x over previous
//
#include <hip/hip_runtime.h>

typedef unsigned short u16;
typedef unsigned int u32;
typedef unsigned long long u64;
typedef _Float16 f16x8 __attribute__((ext_vector_type(8)));
typedef float f32x4 __attribute__((ext_vector_type(4)));

__device__ __forceinline__ u16 f2h(float f) {
  union { _Float16 h; u16 u; } c; c.h = (_Float16)f; return c.u;
}
__device__ __forceinline__ float h2f(u16 v) {
  union { u16 u; _Float16 h; } c; c.u = v; return (float)c.h;
}

__device__ __forceinline__ f32x4 mfma16(f16x8 a, f16x8 b, f32x4 c) {
  return __builtin_amdgcn_mfma_f32_16x16x32_f16(a, b, c, 0, 0, 0);
}

// 8 contiguous fp32 -> 8 fp16 (u16)
__device__ __forceinline__ void ld8f(const float* s, u16* o) {
  float4 a = *(const float4*)s;
  float4 b = *(const float4*)(s + 4);
  o[0] = f2h(a.x); o[1] = f2h(a.y); o[2] = f2h(a.z); o[3] = f2h(a.w);
  o[4] = f2h(b.x); o[5] = f2h(b.y); o[6] = f2h(b.z); o[7] = f2h(b.w);
}

// async global->LDS 16B direct load (CK-style address-space casts).
// LDS dest must be wave-uniform base; HW adds lane*16.
__device__ __forceinline__ void glds16(const u16* g, u16* l) {
  __builtin_amdgcn_global_load_lds(
      reinterpret_cast<const __attribute__((address_space(1))) u32*>(reinterpret_cast<u64>(g)),
      reinterpret_cast<__attribute__((address_space(3))) u32*>(reinterpret_cast<u64>(l)),
      16, 0, 0);
}

// ---------------------------------------------------------------------------
// Pipelined NT tile core: C[BM,BN] += A[BM,K] * B[BN,K]^T, fp16-in-u16,
// K-contiguous operands (lda/ldb in elems). Double-buffered LDS, one barrier
// per K-step, next tile staged via global_load_lds before current compute.
//
// LDS layout per tile: linear [row][32 u16] (64B rows), with XOR slot swizzle:
//   physical 16B-slot c of row r holds logical k-chunk (c ^ ((r>>1)&3)).
// Swizzle applied on the global SOURCE address (stage) and the fragment READ
// (both sides, same involution) -> reads are 2-way bank-aliased max (free).
//
// NNB=true: B is [K][BN] row-major (BN must be 128): B staged via registers
// (issue early) + transposed swizzled ds_write (late), same read layout.
// BM=TM*32, BN=TN*32 (2x2 waves, TMxTN 16x16 mfma tiles per wave). 256 thr.
// ---------------------------------------------------------------------------
template<int TM, int TN, bool NNB>
__device__ __forceinline__ void gemm_core(const u16* __restrict__ A, int lda,
                                          const u16* __restrict__ B, int ldb,
                                          int ksteps, u16* sA, u16* sB, f32x4 acc[TM][TN]) {
  const int t = threadIdx.x;
  const int lane = t & 63, wave = t >> 6;
  const int wm = wave >> 1, wn = wave & 1;
  const int m16 = lane & 15, q4 = lane >> 4;
  constexpr int BM = TM * 32, BN = TN * 32;
  constexpr int TILEA = BM * 32, TILEB = BN * 32;  // u16 per buffer
  constexpr int APF = BM / 64;                      // glds insts/thread for A
  constexpr int BPF = BN / 64;                      // glds insts/thread for B (NT)

  // stage addressing: slot s covers row=s>>2, physical 16B-chunk c=s&3;
  // its global source is logical chunk c ^ ((row>>1)&3).
  int aoff[APF], asl[APF];
#pragma unroll
  for (int p = 0; p < APF; ++p) {
    int s = p * 256 + t, row = s >> 2;
    int kc = (s & 3) ^ ((row >> 1) & 3);
    aoff[p] = row * lda + kc * 8;
    asl[p] = (p * 256 + (t & 192)) * 8;  // wave-uniform LDS u16 base
  }
  int boff[BPF], bsl[BPF];
  if constexpr (!NNB) {
#pragma unroll
    for (int p = 0; p < BPF; ++p) {
      int s = p * 256 + t, row = s >> 2;
      int kc = (s & 3) ^ ((row >> 1) & 3);
      boff[p] = row * ldb + kc * 8;
      bsl[p] = (p * 256 + (t & 192)) * 8;
    }
  }

  // fragment read offsets (u16), loop-invariant
  int aro[TM], bro[TN];
#pragma unroll
  for (int i = 0; i < TM; ++i) {
    int row = wm * TM * 16 + i * 16 + m16;
    aro[i] = row * 32 + ((q4 ^ ((row >> 1) & 3)) << 3);
  }
#pragma unroll
  for (int j = 0; j < TN; ++j) {
    int row = wn * TN * 16 + j * 16 + m16;
    bro[j] = row * 32 + ((q4 ^ ((row >> 1) & 3)) << 3);
  }

  // NNB (transpose) staging constants: thread loads B rows kk,kk+1 at cols bnn..+8
  const int bkk = (t >> 4) * 2;
  const int bnn = (t & 15) * 8;
  const int erot = t & 7;  // rotate e-order per lane: spreads writes over banks (2-way)

  // ---- prologue: stage k-tile 0 into buffer 0
#pragma unroll
  for (int p = 0; p < APF; ++p) glds16(A + aoff[p], sA + asl[p]);
  if constexpr (!NNB) {
#pragma unroll
    for (int p = 0; p < BPF; ++p) glds16(B + boff[p], sB + bsl[p]);
  } else {
    const u16* src = B + (size_t)bkk * ldb + bnn;
    int4 pb0 = *(const int4*)src;
    int4 pb1 = *(const int4*)(src + ldb);
    u16 a0[8], a1[8];
    *(int4*)a0 = pb0; *(int4*)a1 = pb1;
#pragma unroll
    for (int ee = 0; ee < 8; ++ee) {
      int e = (ee + erot) & 7;
      int n = bnn + e;
      int off = n * 32 + ((((bkk >> 3) ^ ((n >> 1) & 3))) << 3) + (bkk & 7);
      *(u32*)&sB[off] = (u32)a0[e] | ((u32)a1[e] << 16);
    }
  }
  __syncthreads();

  int4 nb0, nb1;
#pragma unroll 2
  for (int kt = 0; kt < ksteps; ++kt) {
    const int cur = kt & 1;
    const int nxt = cur ^ 1;
    const bool more = kt + 1 < ksteps;

    // issue next tile's stage early: latency hides under ds_read+MFMA below.
    // target buffer nxt was last READ two steps ago; end-of-previous-iter
    // barrier (with lgkmcnt(0) drain) guarantees those reads completed.
    if (more) {
      const u16* An = A + (kt + 1) * 32;
#pragma unroll
      for (int p = 0; p < APF; ++p) glds16(An + aoff[p], sA + nxt * TILEA + asl[p]);
      if constexpr (!NNB) {
        const u16* Bn = B + (kt + 1) * 32;
#pragma unroll
        for (int p = 0; p < BPF; ++p) glds16(Bn + boff[p], sB + nxt * TILEB + bsl[p]);
      } else {
        const u16* src = B + ((size_t)(kt + 1) * 32 + bkk) * ldb + bnn;
        nb0 = *(const int4*)src;
        nb1 = *(const int4*)(src + ldb);
      }
    }

    // compute on buffer cur
    const u16* dA = sA + cur * TILEA;
    const u16* dB = sB + cur * TILEB;
    f16x8 af[TM], bv[TN];
#pragma unroll
    for (int i = 0; i < TM; ++i) af[i] = *(const f16x8*)&dA[aro[i]];
#pragma unroll
    for (int j = 0; j < TN; ++j) bv[j] = *(const f16x8*)&dB[bro[j]];
#pragma unroll
    for (int i = 0; i < TM; ++i)
#pragma unroll
      for (int j = 0; j < TN; ++j)
        acc[i][j] = mfma16(af[i], bv[j], acc[i][j]);

    // NNB: transposed write of prefetched B regs into buffer nxt (write-late)
    if constexpr (NNB) {
      if (more) {
        u16 a0[8], a1[8];
        *(int4*)a0 = nb0; *(int4*)a1 = nb1;
        u16* wB = sB + nxt * TILEB;
#pragma unroll
        for (int ee = 0; ee < 8; ++ee) {
          int e = (ee + erot) & 7;
          int n = bnn + e;
          int off = n * 32 + ((((bkk >> 3) ^ ((n >> 1) & 3))) << 3) + (bkk & 7);
          *(u32*)&wB[off] = (u32)a0[e] | ((u32)a1[e] << 16);
        }
      }
    }
    // single barrier per K-step: __syncthreads' implicit vmcnt(0)/lgkmcnt(0)
    // drains the glds + reg loads issued this iter; buffer nxt is then ready.
    __syncthreads();
  }
}

// x (fp32, 16.7M) -> xh (fp16)
__global__ __launch_bounds__(256) void cvt_x_kernel(const float* __restrict__ x, u16* __restrict__ xh) {
  size_t i = ((size_t)blockIdx.x * 256 + threadIdx.x) * 8;
  u16 o[8];
  ld8f(x + i, o);
  *(int4*)&xh[i] = *(int4*)o;
}

// q -> qh fp16 + qs row sums; one block per row
__global__ __launch_bounds__(256) void cvt_q_kernel(const float* __restrict__ q, u16* __restrict__ qh,
                                                    float* __restrict__ qs) {
  int row = blockIdx.x, t = threadIdx.x;
  float s = 0.f;
#pragma unroll
  for (int p = 0; p < 2; ++p) {
    size_t i = (size_t)row * 4096 + p * 2048 + t * 8;
    u16 o[8];
    ld8f(q + i, o);
#pragma unroll
    for (int e = 0; e < 8; ++e) s += h2f(o[e]);
    *(int4*)&qh[i] = *(int4*)o;
  }
  for (int off = 32; off; off >>= 1) s += __shfl_xor(s, off);
  __shared__ float wsum[4];
  if ((t & 63) == 0) wsum[t >> 6] = s;
  __syncthreads();
  if (t == 0) qs[row] = wsum[0] + wsum[1] + wsum[2] + wsum[3];
}

// multi-role prep: blocks [0,256): vwT[o][x]=fp16(vw[x][o]); [256,384): kw->fp16; 384: beta=0
__global__ __launch_bounds__(256) void prep_kernel(const float* __restrict__ vw, u16* __restrict__ vwT,
                                                   const float* __restrict__ kw, u16* __restrict__ kwh,
                                                   float* __restrict__ beta) {
  int blk = blockIdx.x, t = threadIdx.x;
  if (blk < 256) {
    __shared__ u16 sT[32 * 33];
    int bx = blk & 15, by = blk >> 4;
#pragma unroll
    for (int p = 0; p < 4; ++p) {
      int idx = p * 256 + t; int r = idx >> 5, c = idx & 31;
      sT[r * 33 + c] = f2h(vw[(size_t)(by * 32 + r) * 512 + bx * 32 + c]);
    }
    __syncthreads();
#pragma unroll
    for (int p = 0; p < 4; ++p) {
      int idx = p * 256 + t; int r = idx >> 5, c = idx & 31;
      vwT[(size_t)(bx * 32 + r) * 512 + by * 32 + c] = sT[c * 33 + r];
    }
  } else if (blk < 384) {
    size_t i = ((size_t)(blk - 256) * 256 + t) * 8;
    u16 o[8];
    ld8f(kw + i, o);
    *(int4*)&kwh[i] = *(int4*)o;
  } else {
    for (int i = t; i < 4096; i += 256) beta[i] = 0.f;
  }
}

// Sh[b][y][o] = sum_n q[y,n]*x[(b,o),n]; 64x64 tiles, K=4096
__global__ __launch_bounds__(256) void sgemm_kernel(const u16* __restrict__ qh, const u16* __restrict__ xh,
                                                    u16* __restrict__ Sh) {
  __shared__ __align__(16) u16 sA[2 * 64 * 32], sB[2 * 64 * 32];
  int rt = blockIdx.x, jt = blockIdx.y;
  f32x4 acc[2][2];
#pragma unroll
  for (int i = 0; i < 2; ++i)
#pragma unroll
    for (int j = 0; j < 2; ++j) acc[i][j] = (f32x4){0.f, 0.f, 0.f, 0.f};
  gemm_core<2, 2, false>(qh + (size_t)jt * 64 * 4096, 4096,
                         xh + (size_t)rt * 64 * 4096, 4096, 128, sA, sB, acc);

  const int t = threadIdx.x, lane = t & 63, wave = t >> 6;
  const int wm = wave >> 1, wn = wave & 1, m16 = lane & 15, q4 = lane >> 4;
  int b = (rt * 64) >> 9, o0 = (rt * 64) & 511;
  u16* Ob = Sh + (size_t)b * 262144;
#pragma unroll
  for (int i = 0; i < 2; ++i)
#pragma unroll
    for (int j = 0; j < 2; ++j)
#pragma unroll
      for (int r = 0; r < 4; ++r) {
        int y = jt * 64 + wm * 32 + i * 16 + q4 * 4 + r;
        int o = o0 + wn * 32 + j * 16 + m16;
        Ob[(size_t)y * 512 + o] = f2h(acc[i][j][r]);
      }
}

// E[b,x,y] = sum_o kw[x,o] * Sh[b][y][o]
__global__ __launch_bounds__(256) void egemm_kernel(const u16* __restrict__ kwh, const u16* __restrict__ Sh,
                                                    float* __restrict__ E) {
  __shared__ __align__(16) u16 sA[2 * 64 * 32], sB[2 * 64 * 32];
  int xt = blockIdx.x >> 3, yt = blockIdx.x & 7, b = blockIdx.y;
  f32x4 acc[2][2];
#pragma unroll
  for (int i = 0; i < 2; ++i)
#pragma unroll
    for (int j = 0; j < 2; ++j) acc[i][j] = (f32x4){0.f, 0.f, 0.f, 0.f};
  gemm_core<2, 2, false>(kwh + (size_t)xt * 64 * 512, 512,
                         Sh + (size_t)b * 262144 + (size_t)yt * 64 * 512, 512, 16, sA, sB, acc);

  const int t = threadIdx.x, lane = t & 63, wave = t >> 6;
  const int wm = wave >> 1, wn = wave & 1, m16 = lane & 15, q4 = lane >> 4;
  float* O = E + ((size_t)b * 512 + xt * 64) * 512 + yt * 64;
#pragma unroll
  for (int i = 0; i < 2; ++i)
#pragma unroll
    for (int j = 0; j < 2; ++j)
#pragma unroll
      for (int r = 0; r < 4; ++r) {
        int row = wm * 32 + i * 16 + q4 * 4 + r;
        int col = wn * 32 + j * 16 + m16;
        O[(size_t)row * 512 + col] = acc[i][j][r];
      }
}

// softmax over y of (E[b,x,y]+kb[x]*qs[y]); writes attT[b][y][x] fp16; beta[b][y] += sum_x att*vb[x]
__global__ __launch_bounds__(256) void softmax_kernel(const float* __restrict__ E, const float* __restrict__ qs,
                                                      const float* __restrict__ kb, const float* __restrict__ vb,
                                                      u16* __restrict__ attT, float* __restrict__ beta) {
  __shared__ float sE[16 * 516];
  __shared__ float sM[16], sS[16];
  int i0 = blockIdx.x * 16, b = blockIdx.y, t = threadIdx.x;
  const float* Eb = E + ((size_t)b * 512 + i0) * 512;
  for (int ch = 0; ch < 32; ++ch) {
    int idx = ch * 256 + t;
    int row = idx >> 9, col = idx & 511;
    sE[row * 516 + col] = Eb[(size_t)row * 512 + col] + kb[i0 + row] * qs[col];
  }
  __syncthreads();
  {
    int row = t >> 4, sub = t & 15;
    float mx = -1e30f;
    for (int ii = 0; ii < 32; ++ii) mx = fmaxf(mx, sE[row * 516 + sub + ii * 16]);
    for (int off = 8; off; off >>= 1) mx = fmaxf(mx, __shfl_xor(mx, off));
    float sm = 0.f;
    for (int ii = 0; ii < 32; ++ii) sm += __expf(sE[row * 516 + sub + ii * 16] - mx);
    for (int off = 8; off; off >>= 1) sm += __shfl_xor(sm, off);
    if (sub == 0) { sM[row] = mx; sS[row] = 1.f / sm; }
  }
  __syncthreads();
  float vbr = vb[i0 + (t & 15)];
  u16* Ob = attT + (size_t)b * 262144;
  for (int ch = 0; ch < 32; ++ch) {
    int idx = ch * 256 + t;
    int r = idx & 15, j = idx >> 4;
    float a = __expf(sE[r * 516 + j] - sM[r]) * sS[r];
    Ob[(size_t)j * 512 + i0 + r] = f2h(a);
    float part = a * vbr;
    for (int off = 8; off; off >>= 1) part += __shfl_xor(part, off);
    if (r == 0) atomicAdd(&beta[b * 512 + j], part);
  }
}

// W[b][c][o] = sum_x attT[b][c][x] * vwT[o][x]
__global__ __launch_bounds__(256) void wgemm_kernel(const u16* __restrict__ attT, const u16* __restrict__ vwT,
                                                    u16* __restrict__ W) {
  __shared__ __align__(16) u16 sA[2 * 64 * 32], sB[2 * 64 * 32];
  int ct = blockIdx.x >> 3, ot = blockIdx.x & 7, b = blockIdx.y;
  f32x4 acc[2][2];
#pragma unroll
  for (int i = 0; i < 2; ++i)
#pragma unroll
    for (int j = 0; j < 2; ++j) acc[i][j] = (f32x4){0.f, 0.f, 0.f, 0.f};
  gemm_core<2, 2, false>(attT + (size_t)b * 262144 + (size_t)ct * 64 * 512, 512,
                         vwT + (size_t)ot * 64 * 512, 512, 16, sA, sB, acc);

  const int t = threadIdx.x, lane = t & 63, wave = t >> 6;
  const int wm = wave >> 1, wn = wave & 1, m16 = lane & 15, q4 = lane >> 4;
  u16* O = W + (size_t)b * 262144 + (size_t)(ct * 64) * 512 + ot * 64;
#pragma unroll
  for (int i = 0; i < 2; ++i)
#pragma unroll
    for (int j = 0; j < 2; ++j)
#pragma unroll
      for (int r = 0; r < 4; ++r) {
        int row = wm * 32 + i * 16 + q4 * 4 + r;
        int col = wn * 32 + j * 16 + m16;
        O[(size_t)row * 512 + col] = f2h(acc[i][j][r]);
      }
}

// out[b,c,n] = gamma*(sum_o W[b,c,o]*xh[b,o,n] + beta[b,c]) + x[b,c,n]  (fp32 out)
__global__ __launch_bounds__(256) void outgemm_kernel(const u16* __restrict__ W, const u16* __restrict__ xh,
                                                      const float* __restrict__ x, const float* __restrict__ beta,
                                                      const float* __restrict__ gm, float* __restrict__ out) {
  __shared__ __align__(16) u16 sA[2 * 128 * 32], sB[2 * 128 * 32];
  int nt = blockIdx.x, ct = blockIdx.y, b = blockIdx.z;
  f32x4 acc[4][4];
#pragma unroll
  for (int i = 0; i < 4; ++i)
#pragma unroll
    for (int j = 0; j < 4; ++j) acc[i][j] = (f32x4){0.f, 0.f, 0.f, 0.f};
  gemm_core<4, 4, true>(W + (size_t)b * 262144 + (size_t)ct * 128 * 512, 512,
                        xh + (size_t)b * 2097152 + nt * 128, 4096, 16, sA, sB, acc);

  const int t = threadIdx.x, lane = t & 63, wave = t >> 6;
  const int wm = wave >> 1, wn = wave & 1, m16 = lane & 15, q4 = lane >> 4;
  float g = gm[0];
#pragma unroll
  for (int i = 0; i < 4; ++i)
#pragma unroll
    for (int j = 0; j < 4; ++j)
#pragma unroll
      for (int r = 0; r < 4; ++r) {
        int c = ct * 128 + wm * 64 + i * 16 + q4 * 4 + r;
        int n = nt * 128 + wn * 64 + j * 16 + m16;
        size_t idx = (size_t)b * 2097152 + (size_t)c * 4096 + n;
        out[idx] = g * (acc[i][j][r] + beta[b * 512 + c]) + x[idx];
      }
}

extern "C" void kernel_launch(void* const* d_in, const int* in_sizes, int n_in,
                              void* d_out, int out_size, void* d_ws, size_t ws_size,
                              hipStream_t stream) {
  const float* x  = (const float*)d_in[0];
  const float* pq = (const float*)d_in[1];
  const float* kw = (const float*)d_in[2];
  const float* kb = (const float*)d_in[3];
  const float* vw = (const float*)d_in[4];
  const float* vb = (const float*)d_in[5];
  const float* gm = (const float*)d_in[6];
  float* out = (float*)d_out;

  // workspace: 53 MB + 32 KB (unchanged layout)
  char* ws = (char*)d_ws;
  u16*   xh   = (u16*)(ws);                            // [0,32M)  fp16 x, live to end
  u16*   qh   = (u16*)(ws + (32ull << 20));            // [32,36M)
  u16*   Sh   = (u16*)(ws + (36ull << 20));            // [36,40M) reused as W after egemm
  u16*   W    = (u16*)(ws + (36ull << 20));
  float* E    = (float*)(ws + (40ull << 20));          // [40,48M) fp32
  u16*   attT = (u16*)(ws + (48ull << 20));            // [48,52M)
  u16*   kwh  = (u16*)(ws + (52ull << 20));            // 512K
  u16*   vwT  = (u16*)(ws + (52ull << 20) + 524288);   // 512K
  char*  sm   = ws + (53ull << 20);                    // small region
  float* qs   = (float*)(sm);
  float* beta = (float*)(sm + 4096);                   // 16K

  cvt_x_kernel<<<dim3(8192), 256, 0, stream>>>(x, xh);
  cvt_q_kernel<<<dim3(512), 256, 0, stream>>>(pq, qh, qs);
  prep_kernel<<<dim3(385), 256, 0, stream>>>(vw, vwT, kw, kwh, beta);
  sgemm_kernel<<<dim3(64, 8), 256, 0, stream>>>(qh, xh, Sh);
  egemm_kernel<<<dim3(64, 8), 256, 0, stream>>>(kwh, Sh, E);
  softmax_kernel<<<dim3(32, 8), 256, 0, stream>>>(E, qs, kb, vb, attT, beta);
  wgemm_kernel<<<dim3(64, 8), 256, 0, stream>>>(attT, vwT, W);
  outgemm_kernel<<<dim3(32, 4, 8), 256, 0, stream>>>(W, xh, x, beta, gm, out);
}

// Round 2
// 238.606 us; speedup vs baseline: 1.0990x; 1.0303x over previous
//
#include <hip/hip_runtime.h>

typedef unsigned short u16;
typedef unsigned int u32;
typedef unsigned long long u64;
typedef _Float16 f16x8 __attribute__((ext_vector_type(8)));
typedef float f32x4 __attribute__((ext_vector_type(4)));

__device__ __forceinline__ u16 f2h(float f) {
  union { _Float16 h; u16 u; } c; c.h = (_Float16)f; return c.u;
}
__device__ __forceinline__ float h2f(u16 v) {
  union { u16 u; _Float16 h; } c; c.u = v; return (float)c.h;
}

__device__ __forceinline__ f32x4 mfma16(f16x8 a, f16x8 b, f32x4 c) {
  return __builtin_amdgcn_mfma_f32_16x16x32_f16(a, b, c, 0, 0, 0);
}

// 8 contiguous fp32 -> 8 fp16 (u16)
__device__ __forceinline__ void ld8f(const float* s, u16* o) {
  float4 a = *(const float4*)s;
  float4 b = *(const float4*)(s + 4);
  o[0] = f2h(a.x); o[1] = f2h(a.y); o[2] = f2h(a.z); o[3] = f2h(a.w);
  o[4] = f2h(b.x); o[5] = f2h(b.y); o[6] = f2h(b.z); o[7] = f2h(b.w);
}

// async global->LDS 16B direct load. LDS dest wave-uniform base; HW adds lane*16.
__device__ __forceinline__ void glds16(const u16* g, u16* l) {
  __builtin_amdgcn_global_load_lds(
      reinterpret_cast<const __attribute__((address_space(1))) u32*>(reinterpret_cast<u64>(g)),
      reinterpret_cast<__attribute__((address_space(3))) u32*>(reinterpret_cast<u64>(l)),
      16, 0, 0);
}

// ---------------------------------------------------------------------------
// Counted-vmcnt pipelined NT tile core: C[BM,BN] += A[BM,K]*B[BN,K]^T.
// fp16-in-u16, K-contiguous operands. Raw s_barrier + s_waitcnt vmcnt(VPI):
// tile t+1's loads stay in flight ACROSS the barrier (only tile t's waited).
//   A: glds-staged, TRIPLE buffered (async landing vs laggard readers: D=3).
//   B (!NNB): glds-staged, triple buffered.
//   B (NNB, [K][BN] row-major, BN=128): reg-load early + transposed swizzled
//      ds_write late, DOUBLE buffered (writes are post-barrier: D=2 safe),
//      lgkmcnt(0) before barrier publishes the writes.
// LDS tile layout: linear [row][32 u16], 16B-chunk c of row r holds logical
// k-chunk c ^ ((r>>1)&3) (same involution on stage source and fragment read).
// BM=TM*32, BN=TN*32 (2x2 waves, TMxTN 16x16 mfma tiles per wave). 256 thr.
// ---------------------------------------------------------------------------
template<int TM, int TN, bool NNB>
__device__ __forceinline__ void gemm_core(const u16* __restrict__ A, int lda,
                                          const u16* __restrict__ B, int ldb,
                                          int ksteps, u16* sA, u16* sB, f32x4 acc[TM][TN]) {
  const int t = threadIdx.x;
  const int lane = t & 63, wave = t >> 6;
  const int wm = wave >> 1, wn = wave & 1;
  const int m16 = lane & 15, q4 = lane >> 4;
  constexpr int BM = TM * 32, BN = TN * 32;
  constexpr int TILEA = BM * 32, TILEB = BN * 32;  // u16 per buffer
  constexpr int APF = BM / 64;                      // glds insts/thread for A
  constexpr int BPF = BN / 64;                      // glds insts/thread for B (NT)
  constexpr int VPI = NNB ? (APF + 2) : (APF + BPF);  // vmem issued per iter

  // A stage addressing: slot s -> row=s>>2, phys chunk c=s&3 holds logical
  // chunk c ^ ((row>>1)&3) (pre-swizzled global source, linear LDS dest).
  int aoff[APF], asl[APF];
#pragma unroll
  for (int p = 0; p < APF; ++p) {
    int s = p * 256 + t, row = s >> 2;
    int kc = (s & 3) ^ ((row >> 1) & 3);
    aoff[p] = row * lda + kc * 8;
    asl[p] = (p * 256 + (t & 192)) * 8;  // wave-uniform LDS u16 base
  }
  int boff[BPF], bsl[BPF];
  if constexpr (!NNB) {
#pragma unroll
    for (int p = 0; p < BPF; ++p) {
      int s = p * 256 + t, row = s >> 2;
      int kc = (s & 3) ^ ((row >> 1) & 3);
      boff[p] = row * ldb + kc * 8;
      bsl[p] = (p * 256 + (t & 192)) * 8;
    }
  }

  // fragment read offsets (u16), loop-invariant
  int aro[TM], bro[TN];
#pragma unroll
  for (int i = 0; i < TM; ++i) {
    int row = wm * TM * 16 + i * 16 + m16;
    aro[i] = row * 32 + ((q4 ^ ((row >> 1) & 3)) << 3);
  }
#pragma unroll
  for (int j = 0; j < TN; ++j) {
    int row = wn * TN * 16 + j * 16 + m16;
    bro[j] = row * 32 + ((q4 ^ ((row >> 1) & 3)) << 3);
  }

  // NNB transpose staging: thread loads B rows bkk,bkk+1 cols bnn..+8;
  // writes column n = bnn + (ee^bpar) at static precomputed offsets.
  // bpar=(t>>2)&1 staggers e-parity across lanes -> 2-way banks (free),
  // all data extracts compile-time-indexed (one cndmask per write).
  const int bkk = (t >> 4) * 2;
  const int bnn = (t & 15) * 8;
  const int bpar = (t >> 2) & 1;
  int bwo[8];
  if constexpr (NNB) {
#pragma unroll
    for (int ee = 0; ee < 8; ++ee) {
      int n = bnn + (ee ^ bpar);
      bwo[ee] = n * 32 + (((bkk >> 3) ^ ((n >> 1) & 3)) << 3) + (bkk & 7);
    }
  }

  // buffer rotation: read R (tile t), stage S (tile t+1), T = third (A only)
  u16 *aR = sA, *aS = sA + TILEA, *aT = sA + 2 * TILEA;
  u16 *bR = sB, *bS = sB + TILEB, *bT = sB + 2 * TILEB;

  // ---- prologue: stage tile 0 into R buffers
  int4 nb0, nb1;
  if constexpr (NNB) {
    const u16* src = B + (size_t)bkk * ldb + bnn;
    nb0 = *(const int4*)src;
    nb1 = *(const int4*)(src + ldb);
    __builtin_amdgcn_sched_barrier(0);  // keep reg loads older than glds
  }
#pragma unroll
  for (int p = 0; p < APF; ++p) glds16(A + aoff[p], aR + asl[p]);
  if constexpr (!NNB) {
#pragma unroll
    for (int p = 0; p < BPF; ++p) glds16(B + boff[p], bR + bsl[p]);
  } else {
    union { int4 v; u16 h[8]; } u0, u1; u0.v = nb0; u1.v = nb1;
    u32 val[8];
#pragma unroll
    for (int e = 0; e < 8; ++e) val[e] = (u32)u0.h[e] | ((u32)u1.h[e] << 16);
#pragma unroll
    for (int ee = 0; ee < 8; ++ee)
      *(u32*)&bR[bwo[ee]] = bpar ? val[ee ^ 1] : val[ee];
  }

#pragma unroll 1
  for (int kt = 0; kt < ksteps; ++kt) {
    const bool more = kt + 1 < ksteps;

    if (more) {
      if constexpr (NNB) {
        const u16* src = B + ((size_t)(kt + 1) * 32 + bkk) * ldb + bnn;
        nb0 = *(const int4*)src;
        nb1 = *(const int4*)(src + ldb);
        __builtin_amdgcn_sched_barrier(0);  // nb loads stay oldest of this iter
      }
      const u16* An = A + (kt + 1) * 32;
#pragma unroll
      for (int p = 0; p < APF; ++p) glds16(An + aoff[p], aS + asl[p]);
      if constexpr (!NNB) {
        const u16* Bn = B + (kt + 1) * 32;
#pragma unroll
        for (int p = 0; p < BPF; ++p) glds16(Bn + boff[p], bS + bsl[p]);
      }
      // tile t's vmem (oldest) must land; tile t+1's VPI may stay in flight.
      if constexpr (NNB)
        asm volatile("s_waitcnt vmcnt(%0) lgkmcnt(0)" :: "n"(VPI) : "memory");
      else
        asm volatile("s_waitcnt vmcnt(%0)" :: "n"(VPI) : "memory");
    } else {
      if constexpr (NNB)
        asm volatile("s_waitcnt vmcnt(0) lgkmcnt(0)" ::: "memory");
      else
        asm volatile("s_waitcnt vmcnt(0)" ::: "memory");
    }
    __builtin_amdgcn_s_barrier();
    __builtin_amdgcn_sched_barrier(0);  // nothing crosses the barrier

    // compute on R buffers
    f16x8 af[TM], bv[TN];
#pragma unroll
    for (int i = 0; i < TM; ++i) af[i] = *(const f16x8*)&aR[aro[i]];
#pragma unroll
    for (int j = 0; j < TN; ++j) bv[j] = *(const f16x8*)&bR[bro[j]];
#pragma unroll
    for (int i = 0; i < TM; ++i)
#pragma unroll
      for (int j = 0; j < TN; ++j)
        acc[i][j] = mfma16(af[i], bv[j], acc[i][j]);

    // NNB: transposed write of prefetched B regs into S (post-barrier: D=2 ok)
    if constexpr (NNB) {
      if (more) {
        union { int4 v; u16 h[8]; } u0, u1; u0.v = nb0; u1.v = nb1;
        u32 val[8];
#pragma unroll
        for (int e = 0; e < 8; ++e) val[e] = (u32)u0.h[e] | ((u32)u1.h[e] << 16);
#pragma unroll
        for (int ee = 0; ee < 8; ++ee)
          *(u32*)&bS[bwo[ee]] = bpar ? val[ee ^ 1] : val[ee];
      }
    }

    // rotate buffers: A mod-3, B mod-3 (!NNB) / mod-2 (NNB)
    { u16* x = aR; aR = aS; aS = aT; aT = x; }
    if constexpr (!NNB) { u16* x = bR; bR = bS; bS = bT; bT = x; }
    else               { u16* x = bR; bR = bS; bS = x; }
  }
}

// x (fp32, 16.7M) -> xh (fp16)
__global__ __launch_bounds__(256) void cvt_x_kernel(const float* __restrict__ x, u16* __restrict__ xh) {
  size_t i = ((size_t)blockIdx.x * 256 + threadIdx.x) * 8;
  u16 o[8];
  ld8f(x + i, o);
  *(int4*)&xh[i] = *(int4*)o;
}

// q -> qh fp16 + qs row sums; one block per row
__global__ __launch_bounds__(256) void cvt_q_kernel(const float* __restrict__ q, u16* __restrict__ qh,
                                                    float* __restrict__ qs) {
  int row = blockIdx.x, t = threadIdx.x;
  float s = 0.f;
#pragma unroll
  for (int p = 0; p < 2; ++p) {
    size_t i = (size_t)row * 4096 + p * 2048 + t * 8;
    u16 o[8];
    ld8f(q + i, o);
#pragma unroll
    for (int e = 0; e < 8; ++e) s += h2f(o[e]);
    *(int4*)&qh[i] = *(int4*)o;
  }
  for (int off = 32; off; off >>= 1) s += __shfl_xor(s, off);
  __shared__ float wsum[4];
  if ((t & 63) == 0) wsum[t >> 6] = s;
  __syncthreads();
  if (t == 0) qs[row] = wsum[0] + wsum[1] + wsum[2] + wsum[3];
}

// multi-role prep: blocks [0,256): vwT[o][x]=fp16(vw[x][o]); [256,384): kw->fp16; 384: beta=0
__global__ __launch_bounds__(256) void prep_kernel(const float* __restrict__ vw, u16* __restrict__ vwT,
                                                   const float* __restrict__ kw, u16* __restrict__ kwh,
                                                   float* __restrict__ beta) {
  int blk = blockIdx.x, t = threadIdx.x;
  if (blk < 256) {
    __shared__ u16 sT[32 * 33];
    int bx = blk & 15, by = blk >> 4;
#pragma unroll
    for (int p = 0; p < 4; ++p) {
      int idx = p * 256 + t; int r = idx >> 5, c = idx & 31;
      sT[r * 33 + c] = f2h(vw[(size_t)(by * 32 + r) * 512 + bx * 32 + c]);
    }
    __syncthreads();
#pragma unroll
    for (int p = 0; p < 4; ++p) {
      int idx = p * 256 + t; int r = idx >> 5, c = idx & 31;
      vwT[(size_t)(bx * 32 + r) * 512 + by * 32 + c] = sT[c * 33 + r];
    }
  } else if (blk < 384) {
    size_t i = ((size_t)(blk - 256) * 256 + t) * 8;
    u16 o[8];
    ld8f(kw + i, o);
    *(int4*)&kwh[i] = *(int4*)o;
  } else {
    for (int i = t; i < 4096; i += 256) beta[i] = 0.f;
  }
}

// Sh[b][y][o] = sum_n q[y,n]*x[(b,o),n]; 64x64 tiles, K=4096
__global__ __launch_bounds__(256) void sgemm_kernel(const u16* __restrict__ qh, const u16* __restrict__ xh,
                                                    u16* __restrict__ Sh) {
  __shared__ __align__(16) u16 sA[3 * 64 * 32], sB[3 * 64 * 32];
  int rt = blockIdx.x, jt = blockIdx.y;
  f32x4 acc[2][2];
#pragma unroll
  for (int i = 0; i < 2; ++i)
#pragma unroll
    for (int j = 0; j < 2; ++j) acc[i][j] = (f32x4){0.f, 0.f, 0.f, 0.f};
  gemm_core<2, 2, false>(qh + (size_t)jt * 64 * 4096, 4096,
                         xh + (size_t)rt * 64 * 4096, 4096, 128, sA, sB, acc);

  const int t = threadIdx.x, lane = t & 63, wave = t >> 6;
  const int wm = wave >> 1, wn = wave & 1, m16 = lane & 15, q4 = lane >> 4;
  int b = (rt * 64) >> 9, o0 = (rt * 64) & 511;
  u16* Ob = Sh + (size_t)b * 262144;
#pragma unroll
  for (int i = 0; i < 2; ++i)
#pragma unroll
    for (int j = 0; j < 2; ++j)
#pragma unroll
      for (int r = 0; r < 4; ++r) {
        int y = jt * 64 + wm * 32 + i * 16 + q4 * 4 + r;
        int o = o0 + wn * 32 + j * 16 + m16;
        Ob[(size_t)y * 512 + o] = f2h(acc[i][j][r]);
      }
}

// E[b,x,y] = sum_o kw[x,o] * Sh[b][y][o]
__global__ __launch_bounds__(256) void egemm_kernel(const u16* __restrict__ kwh, const u16* __restrict__ Sh,
                                                    float* __restrict__ E) {
  __shared__ __align__(16) u16 sA[3 * 64 * 32], sB[3 * 64 * 32];
  int xt = blockIdx.x >> 3, yt = blockIdx.x & 7, b = blockIdx.y;
  f32x4 acc[2][2];
#pragma unroll
  for (int i = 0; i < 2; ++i)
#pragma unroll
    for (int j = 0; j < 2; ++j) acc[i][j] = (f32x4){0.f, 0.f, 0.f, 0.f};
  gemm_core<2, 2, false>(kwh + (size_t)xt * 64 * 512, 512,
                         Sh + (size_t)b * 262144 + (size_t)yt * 64 * 512, 512, 16, sA, sB, acc);

  const int t = threadIdx.x, lane = t & 63, wave = t >> 6;
  const int wm = wave >> 1, wn = wave & 1, m16 = lane & 15, q4 = lane >> 4;
  float* O = E + ((size_t)b * 512 + xt * 64) * 512 + yt * 64;
#pragma unroll
  for (int i = 0; i < 2; ++i)
#pragma unroll
    for (int j = 0; j < 2; ++j)
#pragma unroll
      for (int r = 0; r < 4; ++r) {
        int row = wm * 32 + i * 16 + q4 * 4 + r;
        int col = wn * 32 + j * 16 + m16;
        O[(size_t)row * 512 + col] = acc[i][j][r];
      }
}

// softmax over y of (E[b,x,y]+kb[x]*qs[y]); writes attT[b][y][x] fp16; beta[b][y] += sum_x att*vb[x]
__global__ __launch_bounds__(256) void softmax_kernel(const float* __restrict__ E, const float* __restrict__ qs,
                                                      const float* __restrict__ kb, const float* __restrict__ vb,
                                                      u16* __restrict__ attT, float* __restrict__ beta) {
  __shared__ float sE[16 * 516];
  __shared__ float sM[16], sS[16];
  int i0 = blockIdx.x * 16, b = blockIdx.y, t = threadIdx.x;
  const float* Eb = E + ((size_t)b * 512 + i0) * 512;
  for (int ch = 0; ch < 32; ++ch) {
    int idx = ch * 256 + t;
    int row = idx >> 9, col = idx & 511;
    sE[row * 516 + col] = Eb[(size_t)row * 512 + col] + kb[i0 + row] * qs[col];
  }
  __syncthreads();
  {
    int row = t >> 4, sub = t & 15;
    float mx = -1e30f;
    for (int ii = 0; ii < 32; ++ii) mx = fmaxf(mx, sE[row * 516 + sub + ii * 16]);
    for (int off = 8; off; off >>= 1) mx = fmaxf(mx, __shfl_xor(mx, off));
    float sm = 0.f;
    for (int ii = 0; ii < 32; ++ii) sm += __expf(sE[row * 516 + sub + ii * 16] - mx);
    for (int off = 8; off; off >>= 1) sm += __shfl_xor(sm, off);
    if (sub == 0) { sM[row] = mx; sS[row] = 1.f / sm; }
  }
  __syncthreads();
  float vbr = vb[i0 + (t & 15)];
  u16* Ob = attT + (size_t)b * 262144;
  for (int ch = 0; ch < 32; ++ch) {
    int idx = ch * 256 + t;
    int r = idx & 15, j = idx >> 4;
    float a = __expf(sE[r * 516 + j] - sM[r]) * sS[r];
    Ob[(size_t)j * 512 + i0 + r] = f2h(a);
    float part = a * vbr;
    for (int off = 8; off; off >>= 1) part += __shfl_xor(part, off);
    if (r == 0) atomicAdd(&beta[b * 512 + j], part);
  }
}

// W[b][c][o] = sum_x attT[b][c][x] * vwT[o][x]
__global__ __launch_bounds__(256) void wgemm_kernel(const u16* __restrict__ attT, const u16* __restrict__ vwT,
                                                    u16* __restrict__ W) {
  __shared__ __align__(16) u16 sA[3 * 64 * 32], sB[3 * 64 * 32];
  int ct = blockIdx.x >> 3, ot = blockIdx.x & 7, b = blockIdx.y;
  f32x4 acc[2][2];
#pragma unroll
  for (int i = 0; i < 2; ++i)
#pragma unroll
    for (int j = 0; j < 2; ++j) acc[i][j] = (f32x4){0.f, 0.f, 0.f, 0.f};
  gemm_core<2, 2, false>(attT + (size_t)b * 262144 + (size_t)ct * 64 * 512, 512,
                         vwT + (size_t)ot * 64 * 512, 512, 16, sA, sB, acc);

  const int t = threadIdx.x, lane = t & 63, wave = t >> 6;
  const int wm = wave >> 1, wn = wave & 1, m16 = lane & 15, q4 = lane >> 4;
  u16* O = W + (size_t)b * 262144 + (size_t)(ct * 64) * 512 + ot * 64;
#pragma unroll
  for (int i = 0; i < 2; ++i)
#pragma unroll
    for (int j = 0; j < 2; ++j)
#pragma unroll
      for (int r = 0; r < 4; ++r) {
        int row = wm * 32 + i * 16 + q4 * 4 + r;
        int col = wn * 32 + j * 16 + m16;
        O[(size_t)row * 512 + col] = f2h(acc[i][j][r]);
      }
}

// out[b,c,n] = gamma*(sum_o W[b,c,o]*xh[b,o,n] + beta[b,c]) + x[b,c,n]  (fp32 out)
__global__ __launch_bounds__(256) void outgemm_kernel(const u16* __restrict__ W, const u16* __restrict__ xh,
                                                      const float* __restrict__ x, const float* __restrict__ beta,
                                                      const float* __restrict__ gm, float* __restrict__ out) {
  __shared__ __align__(16) u16 sA[3 * 128 * 32], sB[2 * 128 * 32];
  int nt = blockIdx.x, ct = blockIdx.y, b = blockIdx.z;
  f32x4 acc[4][4];
#pragma unroll
  for (int i = 0; i < 4; ++i)
#pragma unroll
    for (int j = 0; j < 4; ++j) acc[i][j] = (f32x4){0.f, 0.f, 0.f, 0.f};
  gemm_core<4, 4, true>(W + (size_t)b * 262144 + (size_t)ct * 128 * 512, 512,
                        xh + (size_t)b * 2097152 + nt * 128, 4096, 16, sA, sB, acc);

  const int t = threadIdx.x, lane = t & 63, wave = t >> 6;
  const int wm = wave >> 1, wn = wave & 1, m16 = lane & 15, q4 = lane >> 4;
  float g = gm[0];
#pragma unroll
  for (int i = 0; i < 4; ++i)
#pragma unroll
    for (int j = 0; j < 4; ++j)
#pragma unroll
      for (int r = 0; r < 4; ++r) {
        int c = ct * 128 + wm * 64 + i * 16 + q4 * 4 + r;
        int n = nt * 128 + wn * 64 + j * 16 + m16;
        size_t idx = (size_t)b * 2097152 + (size_t)c * 4096 + n;
        out[idx] = g * (acc[i][j][r] + beta[b * 512 + c]) + x[idx];
      }
}

extern "C" void kernel_launch(void* const* d_in, const int* in_sizes, int n_in,
                              void* d_out, int out_size, void* d_ws, size_t ws_size,
                              hipStream_t stream) {
  const float* x  = (const float*)d_in[0];
  const float* pq = (const float*)d_in[1];
  const float* kw = (const float*)d_in[2];
  const float* kb = (const float*)d_in[3];
  const float* vw = (const float*)d_in[4];
  const float* vb = (const float*)d_in[5];
  const float* gm = (const float*)d_in[6];
  float* out = (float*)d_out;

  // workspace: 53 MB + 32 KB (unchanged layout)
  char* ws = (char*)d_ws;
  u16*   xh   = (u16*)(ws);                            // [0,32M)  fp16 x, live to end
  u16*   qh   = (u16*)(ws + (32ull << 20));            // [32,36M)
  u16*   Sh   = (u16*)(ws + (36ull << 20));            // [36,40M) reused as W after egemm
  u16*   W    = (u16*)(ws + (36ull << 20));
  float* E    = (float*)(ws + (40ull << 20));          // [40,48M) fp32
  u16*   attT = (u16*)(ws + (48ull << 20));            // [48,52M)
  u16*   kwh  = (u16*)(ws + (52ull << 20));            // 512K
  u16*   vwT  = (u16*)(ws + (52ull << 20) + 524288);   // 512K
  char*  sm   = ws + (53ull << 20);                    // small region
  float* qs   = (float*)(sm);
  float* beta = (float*)(sm + 4096);                   // 16K

  cvt_x_kernel<<<dim3(8192), 256, 0, stream>>>(x, xh);
  cvt_q_kernel<<<dim3(512), 256, 0, stream>>>(pq, qh, qs);
  prep_kernel<<<dim3(385), 256, 0, stream>>>(vw, vwT, kw, kwh, beta);
  sgemm_kernel<<<dim3(64, 8), 256, 0, stream>>>(qh, xh, Sh);
  egemm_kernel<<<dim3(64, 8), 256, 0, stream>>>(kwh, Sh, E);
  softmax_kernel<<<dim3(32, 8), 256, 0, stream>>>(E, qs, kb, vb, attT, beta);
  wgemm_kernel<<<dim3(64, 8), 256, 0, stream>>>(attT, vwT, W);
  outgemm_kernel<<<dim3(32, 4, 8), 256, 0, stream>>>(W, xh, x, beta, gm, out);
}